// Round 8
// baseline (377.191 us; speedup 1.0000x reference)
//
#include <hip/hip_runtime.h>
#include <cstdint>
#include <cstddef>

#define NEG_SLOPE 0.2f
#define BN_EPS 1e-5f
#define BK_SHIFT 8          // 256-node buckets (scan hierarchy granule)
#define CHUNK 8192          // edges per scatter block
#define DCHUNK 4096         // edges per degree block

typedef _Float16 half4 __attribute__((ext_vector_type(4)));

// ---------------------------------------------------------------------------
// K0: fold b1 + BN(eval) into per-channel scale/shift.
// ---------------------------------------------------------------------------
__global__ void prep_kernel(const float* __restrict__ b1,
                            const float* __restrict__ bn_gamma,
                            const float* __restrict__ bn_beta,
                            const float* __restrict__ bn_mean,
                            const float* __restrict__ bn_var,
                            float* __restrict__ pre0,
                            float* __restrict__ pre1) {
    int t = threadIdx.x;            // 128 threads
    if (t < 128) {
        float sc = rsqrtf(bn_var[t] + BN_EPS) * bn_gamma[t];
        pre0[t] = sc;
        pre1[t] = (b1[t] - bn_mean[t]) * sc + bn_beta[t];
    }
}

// ---------------------------------------------------------------------------
// K1 (R22): degree count — ONE pass over dst half of ei (+self-loops).
// Global atomicAdd per node degree + LDS bucket histogram (bin's proven
// aggregation) flushed once per (block,bucket) to bktsum. Replaces the
// bin kernel's count+scatter and csr's histogram (4 passes -> 1).
// ---------------------------------------------------------------------------
__global__ void deg_kernel(const int* __restrict__ ei, int E, int N, int NBK,
                           int* __restrict__ deg, int* __restrict__ bktsum) {
    __shared__ int cnt[512];
    int T = E + N;
    int tid = threadIdx.x;          // 256
    for (int b = tid; b < NBK; b += 256) cnt[b] = 0;
    __syncthreads();
    int base = blockIdx.x * DCHUNK;
    bool fast = (base + DCHUNK <= E);
    if (fast) {
        for (int k = 0; k < DCHUNK; k += 1024) {
            int i0 = base + k + tid;
            int d0 = ei[E + i0];
            int d1 = ei[E + i0 + 256];
            int d2 = ei[E + i0 + 512];
            int d3 = ei[E + i0 + 768];
            atomicAdd(&deg[d0], 1);
            atomicAdd(&deg[d1], 1);
            atomicAdd(&deg[d2], 1);
            atomicAdd(&deg[d3], 1);
            atomicAdd(&cnt[d0 >> BK_SHIFT], 1);
            atomicAdd(&cnt[d1 >> BK_SHIFT], 1);
            atomicAdd(&cnt[d2 >> BK_SHIFT], 1);
            atomicAdd(&cnt[d3 >> BK_SHIFT], 1);
        }
    } else {
        for (int k = 0; k < DCHUNK; k += 256) {
            int i = base + k + tid;
            if (i < T) {
                int dst = (i < E) ? ei[E + i] : (i - E);
                atomicAdd(&deg[dst], 1);
                atomicAdd(&cnt[dst >> BK_SHIFT], 1);
            }
        }
    }
    __syncthreads();
    for (int b = tid; b < NBK; b += 256) {
        int c = cnt[b];
        if (c) atomicAdd(&bktsum[b], c);
    }
}

// ---------------------------------------------------------------------------
// K2a: exclusive scan of NBK (391) bucket sums. ONE wave; each lane owns a
// contiguous run of ceil(NBK/64) entries: serial local scan + shfl_up
// cross-lane scan of lane totals.
// ---------------------------------------------------------------------------
__global__ void scan_bkt_kernel(const int* __restrict__ bktsum, int NBK,
                                int* __restrict__ bucket_base) {
    int lane = threadIdx.x;         // 64
    int cpl = (NBK + 63) >> 6;
    int beg = lane * cpl;
    int s = 0;
    for (int i = 0; i < cpl; ++i) {
        int b = beg + i;
        if (b < NBK) s += bktsum[b];
    }
    int incl = s;
#pragma unroll
    for (int off = 1; off < 64; off <<= 1) {
        int t = __shfl_up(incl, off);
        if (lane >= off) incl += t;
    }
    int run = incl - s;             // exclusive base for this lane's run
    for (int i = 0; i < cpl; ++i) {
        int b = beg + i;
        if (b < NBK) { bucket_base[b] = run; run += bktsum[b]; }
    }
}

// ---------------------------------------------------------------------------
// K2b: per-bucket degree scan (R20-PROVEN 4-wave shfl scan, absmax-verified)
// + bucket_base offset -> row_beg / row_end / cur. 256 threads, 1 blk/bucket.
// ---------------------------------------------------------------------------
__global__ void scan_row_kernel(const int* __restrict__ deg,
                                const int* __restrict__ bucket_base,
                                int N,
                                int* __restrict__ row_beg,
                                int* __restrict__ row_end,
                                int* __restrict__ cur) {
    __shared__ int wsum[4];
    int b = blockIdx.x;
    int tid = threadIdx.x;          // 256
    int n = (b << BK_SHIFT) + tid;
    int v = (n < N) ? deg[n] : 0;
    int lane = tid & 63;
    int w = tid >> 6;               // wave 0..3
    int incl = v;
#pragma unroll
    for (int off = 1; off < 64; off <<= 1) {
        int t = __shfl_up(incl, off);
        if (lane >= off) incl += t;
    }
    if (lane == 63) wsum[w] = incl;
    __syncthreads();
    int prefix = 0;
#pragma unroll
    for (int i = 0; i < 3; ++i)
        if (i < w) prefix += wsum[i];
    incl += prefix;
    int base = bucket_base[b];
    if (n < N) {
        int excl = incl - v;
        row_beg[n] = base + excl;
        row_end[n] = base + incl;
        cur[n]     = base + excl;
    }
}

// ---------------------------------------------------------------------------
// K3 (fused): blockIdx < NSC -> scatter; else gemm1 (R18-PROVEN 8-node
// body — R21's 16-node/float2 variant was neutral-to-negative, retired).
// scatter: one pass over ei; pos = atomicAdd(cur[dst]); csr_src[pos]=src.
// Fused so scatter's ~15us hides under gemm's ~80us (R20: overlap ~12us).
// gemm: x rows staged in LDS, wave-uniform ds_read_b128 broadcasts,
// #pragma unroll 2 ONLY (R16 full unroll spilled, 1.9GB scratch).
// ---------------------------------------------------------------------------
__global__ void scatter_gemm_kernel(// gemm args
                                    const float* __restrict__ x,
                                    const float* __restrict__ W1,
                                    const float* __restrict__ att_s,
                                    const float* __restrict__ att_d,
                                    _Float16* __restrict__ h0,
                                    float* __restrict__ as1,
                                    float* __restrict__ ad1,
                                    int N,
                                    // scatter args
                                    const int* __restrict__ ei, int E,
                                    int* __restrict__ cur,
                                    int* __restrict__ csr_src,
                                    int NSC) {
    __shared__ float xs[512];       // 8 x-rows (gemm path only)
    if (blockIdx.x < NSC) {
        int T = E + N;
        int tid = threadIdx.x;
        int base = blockIdx.x * CHUNK;
        bool fast = (base + CHUNK <= E);
        if (fast) {
            for (int k = 0; k < CHUNK; k += 1024) {
                int i0 = base + k + tid;
                int s0 = ei[i0];
                int s1 = ei[i0 + 256];
                int s2 = ei[i0 + 512];
                int s3 = ei[i0 + 768];
                int d0 = ei[E + i0];
                int d1 = ei[E + i0 + 256];
                int d2 = ei[E + i0 + 512];
                int d3 = ei[E + i0 + 768];
                int p0 = atomicAdd(&cur[d0], 1);
                int p1 = atomicAdd(&cur[d1], 1);
                int p2 = atomicAdd(&cur[d2], 1);
                int p3 = atomicAdd(&cur[d3], 1);
                csr_src[p0] = s0;
                csr_src[p1] = s1;
                csr_src[p2] = s2;
                csr_src[p3] = s3;
            }
        } else {
            for (int k = 0; k < CHUNK; k += 256) {
                int i = base + k + tid;
                if (i < T) {
                    int src, dst;
                    if (i < E) { src = ei[i]; dst = ei[E + i]; }
                    else       { src = i - E; dst = src; }
                    int p = atomicAdd(&cur[dst], 1);
                    csr_src[p] = src;
                }
            }
        }
        return;
    }
    // ----- gemm path: 8 nodes per block, 4 per thread (W1 reuse x4)
    int bid = blockIdx.x - NSC;
    int tid = threadIdx.x;
    int n0b = bid * 8;
    if (n0b >= N) return;
    {   // cooperative stage: 8 rows x 64 floats = 2KB, coalesced loads
        const float* __restrict__ xb = x + (size_t)n0b * 64;
        int lim = N - n0b; if (lim > 8) lim = 8;
        int nf = lim * 64;
        for (int i = tid; i < 512; i += 256)
            xs[i] = (i < nf) ? xb[i] : 0.f;
    }
    __syncthreads();
    int c = tid & 127;
    int pair = __builtin_amdgcn_readfirstlane(tid >> 7);
    int n0 = n0b + pair * 4;
    if (n0 >= N) return;
    float acc[4] = {0.f, 0.f, 0.f, 0.f};
    const float4* __restrict__ xq = (const float4*)&xs[pair * 256];
#pragma unroll 2
    for (int kk = 0; kk < 16; ++kk) {
        float4 x0 = xq[kk];         // uniform addr -> broadcast ds_read_b128
        float4 x1 = xq[16 + kk];
        float4 x2 = xq[32 + kk];
        float4 x3 = xq[48 + kk];
        const float* __restrict__ wp = &W1[kk * 4 * 128 + c];
        float w0 = wp[0];
        float w1 = wp[128];
        float w2 = wp[256];
        float w3 = wp[384];
        acc[0] = fmaf(x0.x, w0, acc[0]); acc[0] = fmaf(x0.y, w1, acc[0]);
        acc[0] = fmaf(x0.z, w2, acc[0]); acc[0] = fmaf(x0.w, w3, acc[0]);
        acc[1] = fmaf(x1.x, w0, acc[1]); acc[1] = fmaf(x1.y, w1, acc[1]);
        acc[1] = fmaf(x1.z, w2, acc[1]); acc[1] = fmaf(x1.w, w3, acc[1]);
        acc[2] = fmaf(x2.x, w0, acc[2]); acc[2] = fmaf(x2.y, w1, acc[2]);
        acc[2] = fmaf(x2.z, w2, acc[2]); acc[2] = fmaf(x2.w, w3, acc[2]);
        acc[3] = fmaf(x3.x, w0, acc[3]); acc[3] = fmaf(x3.y, w1, acc[3]);
        acc[3] = fmaf(x3.z, w2, acc[3]); acc[3] = fmaf(x3.w, w3, acc[3]);
    }
    float asc = att_s[c], adc = att_d[c];
    int head = c >> 5;
    int nn = N - n0; if (nn > 4) nn = 4;
#pragma unroll
    for (int i = 0; i < 4; ++i) {
        if (i >= nn) break;
        int n = n0 + i;
        h0[(size_t)n * 128 + c] = (_Float16)acc[i];
        float s = acc[i] * asc;
        float d = acc[i] * adc;
#pragma unroll
        for (int off = 16; off >= 1; off >>= 1) {
            s += __shfl_xor(s, off);
            d += __shfl_xor(d, off);
        }
        if ((threadIdx.x & 31) == 0) {
            as1[(size_t)n * 4 + head] = s;
            ad1[(size_t)n * 4 + head] = d;
        }
    }
}

// ---------------------------------------------------------------------------
// K4: layer-1 gather + finalize — R18-PROVEN body (84.3 us, pinned).
// ONE WAVE per dst node (block 256 = 4 nodes); 2x32-lane edge-groups;
// half4 h0 loads; register accumulators; shfl combine; prefolded pre0/pre1;
// __expf epilogue + uint32 offsets (R17-proven). Consumes the new direct
// CSR (identical row_beg/row_end/csr_src semantics; row order differs only
// in summation order).
// ---------------------------------------------------------------------------
__global__ void gather1_kernel(const int* __restrict__ row_beg,
                               const int* __restrict__ row_end,
                               const int* __restrict__ csr_src,
                               const half4* __restrict__ h0,
                               const float* __restrict__ as1,
                               const float* __restrict__ ad1,
                               const float* __restrict__ pre0,
                               const float* __restrict__ pre1,
                               const float* __restrict__ W2,
                               float* __restrict__ h2, int N) {
    int n = blockIdx.x * 4 + (threadIdx.x >> 6);
    if (n >= N) return;
    int lane = threadIdx.x & 63;
    int sub  = lane & 31;           // half4 index within the 128-ch row
    int grp  = lane >> 5;           // which edge of the pair
    int head = sub >> 3;            // channels 4*sub..4*sub+3 are in this head
    float ad = ad1[((unsigned)n << 2) + head];
    int beg = row_beg[n];
    int end = row_end[n];
    float4 acc = make_float4(0.f, 0.f, 0.f, 0.f);
    float den = 0.f;
#pragma unroll 2
    for (int j = beg + grp; j < end; j += 2) {
        int src = csr_src[j];
        float as = as1[((unsigned)src << 2) + head];
        float lg = as + ad;
        float l = fmaf(NEG_SLOPE, fminf(lg, 0.f), fmaxf(lg, 0.f));
        float w = __expf(l);
        half4 hv = h0[((unsigned)src << 5) + sub];
        acc.x = fmaf(w, (float)hv.x, acc.x);
        acc.y = fmaf(w, (float)hv.y, acc.y);
        acc.z = fmaf(w, (float)hv.z, acc.z);
        acc.w = fmaf(w, (float)hv.w, acc.w);
        den += w;
    }
    acc.x += __shfl_xor(acc.x, 32);
    acc.y += __shfl_xor(acc.y, 32);
    acc.z += __shfl_xor(acc.z, 32);
    acc.w += __shfl_xor(acc.w, 32);
    den   += __shfl_xor(den, 32);
    float inv = 1.f / (den + 1e-16f);
    int c = sub * 4;
    float v0 = fmaf(acc.x * inv, pre0[c],     pre1[c]);
    float v1 = fmaf(acc.y * inv, pre0[c + 1], pre1[c + 1]);
    float v2 = fmaf(acc.z * inv, pre0[c + 2], pre1[c + 2]);
    float v3 = fmaf(acc.w * inv, pre0[c + 3], pre1[c + 3]);
    v0 = v0 > 0.f ? v0 : __expf(v0) - 1.f;
    v1 = v1 > 0.f ? v1 : __expf(v1) - 1.f;
    v2 = v2 > 0.f ? v2 : __expf(v2) - 1.f;
    v3 = v3 > 0.f ? v3 : __expf(v3) - 1.f;
    float t = v0 * W2[c] + v1 * W2[c + 1] + v2 * W2[c + 2] + v3 * W2[c + 3];
#pragma unroll
    for (int off = 16; off >= 1; off >>= 1) t += __shfl_xor(t, off);
    if (lane == 0) h2[n] = t;
}

// ---------------------------------------------------------------------------
// K5: layer-2 gather (R7-proven). 16-lane group per dst node
// (block 256 = 16 nodes); mean degree ~17 -> lanes ~fully utilized.
// ---------------------------------------------------------------------------
__global__ void gather2_kernel(const int* __restrict__ row_beg,
                               const int* __restrict__ row_end,
                               const int* __restrict__ csr_src,
                               const float* __restrict__ h2,
                               const float* __restrict__ att_s2,
                               const float* __restrict__ att_d2,
                               const float* __restrict__ b2,
                               float* __restrict__ out, int N) {
    int n = blockIdx.x * 16 + (threadIdx.x >> 4);
    if (n >= N) return;
    int lane = threadIdx.x & 15;
    int beg = row_beg[n];
    int end = row_end[n];
    float a_s = att_s2[0];
    float a_d = att_d2[0];
    float hd = h2[n];
    float num = 0.f, den = 0.f;
    for (int j = beg + lane; j < end; j += 16) {
        int src = csr_src[j];
        float hs = h2[src];
        float lg = hs * a_s + hd * a_d;
        float l = fmaf(NEG_SLOPE, fminf(lg, 0.f), fmaxf(lg, 0.f));
        float w = __expf(l);
        num += w * hs;
        den += w;
    }
#pragma unroll
    for (int off = 8; off >= 1; off >>= 1) {
        num += __shfl_xor(num, off);
        den += __shfl_xor(den, off);
    }
    if (lane == 0) out[n] = num / (den + 1e-16f) + b2[0];
}

extern "C" void kernel_launch(void* const* d_in, const int* in_sizes, int n_in,
                              void* d_out, int out_size, void* d_ws, size_t ws_size,
                              hipStream_t stream) {
    const float* x     = (const float*)d_in[0];
    const int*   ei    = (const int*)  d_in[1];
    const float* W1    = (const float*)d_in[2];
    const float* atts1 = (const float*)d_in[3];
    const float* attd1 = (const float*)d_in[4];
    const float* b1    = (const float*)d_in[5];
    const float* W2    = (const float*)d_in[6];
    const float* atts2 = (const float*)d_in[7];
    const float* attd2 = (const float*)d_in[8];
    const float* b2    = (const float*)d_in[9];
    const float* bn_g  = (const float*)d_in[10];
    const float* bn_b  = (const float*)d_in[11];
    const float* bn_m  = (const float*)d_in[12];
    const float* bn_v  = (const float*)d_in[13];

    const int N = in_sizes[0] / 64;     // 100000
    const int E = in_sizes[1] / 2;      // 1600000
    const int T = E + N;
    const int NBK = (N + 255) >> BK_SHIFT;            // 391 buckets
    const int NDG = (T + DCHUNK - 1) / DCHUNK;        // degree blocks
    const int NSC = (T + CHUNK - 1) / CHUNK;          // scatter blocks
    const int NGB = (N + 7) / 8;                      // gemm blocks

    // workspace layout (manual alignment)
    char* p = (char*)d_ws;
    auto alloc = [&](size_t bytes, size_t align) -> void* {
        uintptr_t q = ((uintptr_t)p + align - 1) & ~(uintptr_t)(align - 1);
        p = (char*)(q + bytes);
        return (void*)q;
    };
    _Float16* h0      = (_Float16*)alloc((size_t)N * 128 * 2, 16);
    float* as1        = (float*)alloc((size_t)N * 4 * 4, 16);
    float* ad1        = (float*)alloc((size_t)N * 4 * 4, 16);
    float* h2         = (float*)alloc((size_t)N * 4, 16);
    float* pre0       = (float*)alloc(128 * 4, 16);
    float* pre1       = (float*)alloc(128 * 4, 16);
    int*   row_beg    = (int*)alloc((size_t)N * 4, 16);
    int*   row_end    = (int*)alloc((size_t)N * 4, 16);
    int*   deg        = (int*)alloc(((size_t)N + 512) * 4, 16); // deg + bktsum
    int*   bktsum     = deg + N;
    int*   bucket_base= (int*)alloc(512 * 4, 16);
    int*   cur        = (int*)alloc((size_t)N * 4, 16);
    int*   csr_src    = (int*)alloc((size_t)T * 4, 16);

    // zero deg + bktsum (one contiguous memset; graph-capture-safe)
    hipMemsetAsync(deg, 0, ((size_t)N + 512) * 4, stream);

    prep_kernel<<<1, 128, 0, stream>>>(b1, bn_g, bn_b, bn_m, bn_v, pre0, pre1);

    deg_kernel<<<NDG, 256, 0, stream>>>(ei, E, N, NBK, deg, bktsum);

    scan_bkt_kernel<<<1, 64, 0, stream>>>(bktsum, NBK, bucket_base);

    scan_row_kernel<<<NBK, 256, 0, stream>>>(deg, bucket_base, N,
                                             row_beg, row_end, cur);

    scatter_gemm_kernel<<<NSC + NGB, 256, 0, stream>>>(
        x, W1, atts1, attd1, h0, as1, ad1, N,
        ei, E, cur, csr_src, NSC);

    gather1_kernel<<<(N + 3) / 4, 256, 0, stream>>>(
        row_beg, row_end, csr_src, (const half4*)h0, as1, ad1, pre0, pre1,
        W2, h2, N);

    gather2_kernel<<<(N + 15) / 16, 256, 0, stream>>>(
        row_beg, row_end, csr_src, h2, atts2, attd2, b2, (float*)d_out, N);
}

// Round 9
// 255.057 us; speedup vs baseline: 1.4788x; 1.4788x over previous
//
#include <hip/hip_runtime.h>
#include <cstdint>
#include <cstddef>

#define NEG_SLOPE 0.2f
#define BN_EPS 1e-5f
#define BK_SHIFT 8          // 256 nodes per bucket (bin-optimal; R14's 64 hurt bin)
#define MAXBK 512           // supports N <= 131072
#define CHUNK 8192          // edges per binning block (CHUNK sweep was flat)
#define CAP 8192            // slots per bucket (mean fill 4352, +58 sigma)

typedef _Float16 half4 __attribute__((ext_vector_type(4)));

// ---------------------------------------------------------------------------
// K0: fold b1 + BN(eval) into per-channel scale/shift, zero bucket cursors.
// ---------------------------------------------------------------------------
__global__ void prep_kernel(const float* __restrict__ b1,
                            const float* __restrict__ bn_gamma,
                            const float* __restrict__ bn_beta,
                            const float* __restrict__ bn_mean,
                            const float* __restrict__ bn_var,
                            float* __restrict__ pre0,
                            float* __restrict__ pre1,
                            int* __restrict__ bucket_cursor) {
    int t = threadIdx.x;            // 512 threads
    if (t < 128) {
        float sc = rsqrtf(bn_var[t] + BN_EPS) * bn_gamma[t];
        pre0[t] = sc;
        pre1[t] = (b1[t] - bn_mean[t]) * sc + bn_beta[t];
    }
    if (t < MAXBK) bucket_cursor[t] = 0;
}

// ---------------------------------------------------------------------------
// K1 (fused, R18-PROVEN — best total 257.1 us): blockIdx < NCH -> binning;
// else gemm1.
// bin: LDS histogram over 256-node buckets -> one reservation per
// (block,bucket) -> compact packed writes  word = (dst&255)<<24 | src.
// The bucket-local write pattern is LOAD-BEARING: R22's direct random
// scatter showed 136 MB WRITE_SIZE (16x line amplification) vs ~40 MB here.
// gemm: x rows staged in LDS (2KB coalesced cooperative load), wave-uniform
// ds_read_b128 broadcasts, #pragma unroll 2 ONLY (R16 full unroll spilled:
// 1.9 GB scratch). 8 nodes/block (R21's 16-node float2 variant was
// neutral-to-negative, retired).
// ---------------------------------------------------------------------------
__global__ void gemm_bin_kernel(// gemm args
                                const float* __restrict__ x,
                                const float* __restrict__ W1,
                                const float* __restrict__ att_s,
                                const float* __restrict__ att_d,
                                _Float16* __restrict__ h0,
                                float* __restrict__ as1,
                                float* __restrict__ ad1,
                                int N,
                                // bin args
                                const int* __restrict__ ei, int E, int NBK,
                                int* __restrict__ bucket_cursor,
                                unsigned int* __restrict__ binned,
                                int NCH) {
    __shared__ int cnt[MAXBK];
    __shared__ int gstart[MAXBK];
    __shared__ int cur[MAXBK];
    __shared__ float xs[512];       // 8 x-rows (gemm path only)
    if (blockIdx.x < NCH) {
        int T = E + N;
        int tid = threadIdx.x;
        for (int b = tid; b < NBK; b += 256) { cnt[b] = 0; cur[b] = 0; }
        __syncthreads();
        int base = blockIdx.x * CHUNK;
        bool fast = (base + CHUNK <= E);    // whole chunk is real edges
        if (fast) {
            // ---- count pass, 4 loads in flight per iteration
            for (int k = 0; k < CHUNK; k += 1024) {
                int i0 = base + k + tid;
                int d0 = ei[E + i0];
                int d1 = ei[E + i0 + 256];
                int d2 = ei[E + i0 + 512];
                int d3 = ei[E + i0 + 768];
                atomicAdd(&cnt[d0 >> BK_SHIFT], 1);
                atomicAdd(&cnt[d1 >> BK_SHIFT], 1);
                atomicAdd(&cnt[d2 >> BK_SHIFT], 1);
                atomicAdd(&cnt[d3 >> BK_SHIFT], 1);
            }
        } else {
            for (int k = 0; k < CHUNK; k += 256) {
                int i = base + k + tid;
                if (i < T) {
                    int dst = (i < E) ? ei[E + i] : (i - E);
                    atomicAdd(&cnt[dst >> BK_SHIFT], 1);
                }
            }
        }
        __syncthreads();
        for (int b = tid; b < NBK; b += 256) {
            int c = cnt[b];
            if (c) gstart[b] = atomicAdd(&bucket_cursor[b], c);
        }
        __syncthreads();
        if (fast) {
            // ---- scatter pass, 8 loads in flight per iteration
            for (int k = 0; k < CHUNK; k += 1024) {
                int i0 = base + k + tid;
                int s0 = ei[i0];
                int s1 = ei[i0 + 256];
                int s2 = ei[i0 + 512];
                int s3 = ei[i0 + 768];
                int d0 = ei[E + i0];
                int d1 = ei[E + i0 + 256];
                int d2 = ei[E + i0 + 512];
                int d3 = ei[E + i0 + 768];
                int b0 = d0 >> BK_SHIFT, b1 = d1 >> BK_SHIFT;
                int b2 = d2 >> BK_SHIFT, b3 = d3 >> BK_SHIFT;
                int p0 = gstart[b0] + atomicAdd(&cur[b0], 1);
                int p1 = gstart[b1] + atomicAdd(&cur[b1], 1);
                int p2 = gstart[b2] + atomicAdd(&cur[b2], 1);
                int p3 = gstart[b3] + atomicAdd(&cur[b3], 1);
                if (p0 < CAP) binned[(size_t)b0 * CAP + p0] =
                    (unsigned int)s0 | ((unsigned int)(d0 & 255) << 24);
                if (p1 < CAP) binned[(size_t)b1 * CAP + p1] =
                    (unsigned int)s1 | ((unsigned int)(d1 & 255) << 24);
                if (p2 < CAP) binned[(size_t)b2 * CAP + p2] =
                    (unsigned int)s2 | ((unsigned int)(d2 & 255) << 24);
                if (p3 < CAP) binned[(size_t)b3 * CAP + p3] =
                    (unsigned int)s3 | ((unsigned int)(d3 & 255) << 24);
            }
        } else {
            for (int k = 0; k < CHUNK; k += 256) {
                int i = base + k + tid;
                if (i < T) {
                    int src, dst;
                    if (i < E) { src = ei[i]; dst = ei[E + i]; }
                    else       { src = i - E; dst = src; }
                    int b = dst >> BK_SHIFT;
                    int lp = gstart[b] + atomicAdd(&cur[b], 1);
                    if (lp < CAP)
                        binned[(size_t)b * CAP + lp] =
                            (unsigned int)src | ((unsigned int)(dst & 255) << 24);
                }
            }
        }
        return;
    }
    // ----- gemm path: 8 nodes per block, 4 per thread (W1 reuse x4)
    int bid = blockIdx.x - NCH;
    int tid = threadIdx.x;
    int n0b = bid * 8;
    if (n0b >= N) return;
    {   // cooperative stage: 8 rows x 64 floats = 2KB, coalesced loads
        const float* __restrict__ xb = x + (size_t)n0b * 64;
        int lim = N - n0b; if (lim > 8) lim = 8;
        int nf = lim * 64;
        for (int i = tid; i < 512; i += 256)
            xs[i] = (i < nf) ? xb[i] : 0.f;
    }
    __syncthreads();
    int c = tid & 127;
    int pair = __builtin_amdgcn_readfirstlane(tid >> 7);
    int n0 = n0b + pair * 4;
    if (n0 >= N) return;
    float acc[4] = {0.f, 0.f, 0.f, 0.f};
    const float4* __restrict__ xq = (const float4*)&xs[pair * 256];
#pragma unroll 2
    for (int kk = 0; kk < 16; ++kk) {
        float4 x0 = xq[kk];         // uniform addr -> broadcast ds_read_b128
        float4 x1 = xq[16 + kk];
        float4 x2 = xq[32 + kk];
        float4 x3 = xq[48 + kk];
        const float* __restrict__ wp = &W1[kk * 4 * 128 + c];
        float w0 = wp[0];
        float w1 = wp[128];
        float w2 = wp[256];
        float w3 = wp[384];
        acc[0] = fmaf(x0.x, w0, acc[0]); acc[0] = fmaf(x0.y, w1, acc[0]);
        acc[0] = fmaf(x0.z, w2, acc[0]); acc[0] = fmaf(x0.w, w3, acc[0]);
        acc[1] = fmaf(x1.x, w0, acc[1]); acc[1] = fmaf(x1.y, w1, acc[1]);
        acc[1] = fmaf(x1.z, w2, acc[1]); acc[1] = fmaf(x1.w, w3, acc[1]);
        acc[2] = fmaf(x2.x, w0, acc[2]); acc[2] = fmaf(x2.y, w1, acc[2]);
        acc[2] = fmaf(x2.z, w2, acc[2]); acc[2] = fmaf(x2.w, w3, acc[2]);
        acc[3] = fmaf(x3.x, w0, acc[3]); acc[3] = fmaf(x3.y, w1, acc[3]);
        acc[3] = fmaf(x3.z, w2, acc[3]); acc[3] = fmaf(x3.w, w3, acc[3]);
    }
    float asc = att_s[c], adc = att_d[c];
    int head = c >> 5;
    int nn = N - n0; if (nn > 4) nn = 4;
#pragma unroll
    for (int i = 0; i < 4; ++i) {
        if (i >= nn) break;
        int n = n0 + i;
        h0[(size_t)n * 128 + c] = (_Float16)acc[i];
        float s = acc[i] * asc;
        float d = acc[i] * adc;
#pragma unroll
        for (int off = 16; off >= 1; off >>= 1) {
            s += __shfl_xor(s, off);
            d += __shfl_xor(d, off);
        }
        if ((threadIdx.x & 31) == 0) {
            as1[(size_t)n * 4 + head] = s;
            ad1[(size_t)n * 4 + head] = d;
        }
    }
}

// ---------------------------------------------------------------------------
// K2: per-bucket finalize. R20-carried scan: wave-level __shfl_up +
// 4-entry cross-wave combine (19 barriers -> 4; absmax bit-identical in
// R20/R21/R22). Histogram and scatter passes R14-proven. 1024 threads,
// one block per 256-node bucket.
// ---------------------------------------------------------------------------
__global__ void csr_kernel(const unsigned int* __restrict__ binned,
                           const int* __restrict__ bucket_cursor,
                           int N,
                           int* __restrict__ row_beg,
                           int* __restrict__ row_end,
                           int* __restrict__ csr_src) {
    __shared__ int cnt[256];
    __shared__ int cur[256];
    __shared__ int wsum[4];
    int b = blockIdx.x;
    int tid = threadIdx.x;          // 1024 threads
    int n0 = b << BK_SHIFT;
    int nr = N - n0; if (nr > 256) nr = 256;
    int tot = bucket_cursor[b];
    if (tot > CAP) tot = CAP;
    size_t base = (size_t)b * CAP;
    if (tid < 256) cnt[tid] = 0;
    __syncthreads();
    for (int j = tid; j < tot; j += 1024) {
        atomicAdd(&cnt[binned[base + j] >> 24], 1);
    }
    __syncthreads();
    int v = 0, incl = 0;
    int lane = tid & 63;
    int w = tid >> 6;               // wave id 0..15 (0..3 active in scan)
    if (tid < 256) {
        v = cnt[tid];
        incl = v;
#pragma unroll
        for (int off = 1; off < 64; off <<= 1) {
            int t = __shfl_up(incl, off);
            if (lane >= off) incl += t;
        }
        if (lane == 63) wsum[w] = incl;
    }
    __syncthreads();
    if (tid < 256) {
        int prefix = 0;
#pragma unroll
        for (int i = 0; i < 3; ++i)
            if (i < w) prefix += wsum[i];
        incl += prefix;
        int excl = incl - v;
        cur[tid] = excl;
        if (tid < nr) {
            row_beg[n0 + tid] = (int)base + excl;
            row_end[n0 + tid] = (int)base + incl;
        }
    }
    __syncthreads();
    for (int j = tid; j < tot; j += 1024) {
        unsigned int wv = binned[base + j];
        int pos = atomicAdd(&cur[wv >> 24], 1);
        csr_src[base + pos] = (int)(wv & 0xFFFFFFu);
    }
}

// ---------------------------------------------------------------------------
// K3: layer-1 gather + finalize — R18-PROVEN body (84.3 us, pinned).
// ONE WAVE per dst node (block 256 = 4 nodes); 2x32-lane edge-groups;
// half4 h0 loads; register accumulators; shfl combine; prefolded pre0/pre1;
// __expf epilogue + uint32 offsets (R17-proven). R19's SW-pipeline retired
// (+2 us).
// ---------------------------------------------------------------------------
__global__ void gather1_kernel(const int* __restrict__ row_beg,
                               const int* __restrict__ row_end,
                               const int* __restrict__ csr_src,
                               const half4* __restrict__ h0,
                               const float* __restrict__ as1,
                               const float* __restrict__ ad1,
                               const float* __restrict__ pre0,
                               const float* __restrict__ pre1,
                               const float* __restrict__ W2,
                               float* __restrict__ h2, int N) {
    int n = blockIdx.x * 4 + (threadIdx.x >> 6);
    if (n >= N) return;
    int lane = threadIdx.x & 63;
    int sub  = lane & 31;           // half4 index within the 128-ch row
    int grp  = lane >> 5;           // which edge of the pair
    int head = sub >> 3;            // channels 4*sub..4*sub+3 are in this head
    float ad = ad1[((unsigned)n << 2) + head];
    int beg = row_beg[n];
    int end = row_end[n];
    float4 acc = make_float4(0.f, 0.f, 0.f, 0.f);
    float den = 0.f;
#pragma unroll 2
    for (int j = beg + grp; j < end; j += 2) {
        int src = csr_src[j];
        float as = as1[((unsigned)src << 2) + head];
        float lg = as + ad;
        float l = fmaf(NEG_SLOPE, fminf(lg, 0.f), fmaxf(lg, 0.f));
        float w = __expf(l);
        half4 hv = h0[((unsigned)src << 5) + sub];
        acc.x = fmaf(w, (float)hv.x, acc.x);
        acc.y = fmaf(w, (float)hv.y, acc.y);
        acc.z = fmaf(w, (float)hv.z, acc.z);
        acc.w = fmaf(w, (float)hv.w, acc.w);
        den += w;
    }
    acc.x += __shfl_xor(acc.x, 32);
    acc.y += __shfl_xor(acc.y, 32);
    acc.z += __shfl_xor(acc.z, 32);
    acc.w += __shfl_xor(acc.w, 32);
    den   += __shfl_xor(den, 32);
    float inv = 1.f / (den + 1e-16f);
    int c = sub * 4;
    float v0 = fmaf(acc.x * inv, pre0[c],     pre1[c]);
    float v1 = fmaf(acc.y * inv, pre0[c + 1], pre1[c + 1]);
    float v2 = fmaf(acc.z * inv, pre0[c + 2], pre1[c + 2]);
    float v3 = fmaf(acc.w * inv, pre0[c + 3], pre1[c + 3]);
    v0 = v0 > 0.f ? v0 : __expf(v0) - 1.f;
    v1 = v1 > 0.f ? v1 : __expf(v1) - 1.f;
    v2 = v2 > 0.f ? v2 : __expf(v2) - 1.f;
    v3 = v3 > 0.f ? v3 : __expf(v3) - 1.f;
    float t = v0 * W2[c] + v1 * W2[c + 1] + v2 * W2[c + 2] + v3 * W2[c + 3];
#pragma unroll
    for (int off = 16; off >= 1; off >>= 1) t += __shfl_xor(t, off);
    if (lane == 0) h2[n] = t;
}

// ---------------------------------------------------------------------------
// K4: layer-2 gather (R7-proven). 16-lane group per dst node
// (block 256 = 16 nodes); mean degree ~17 -> lanes ~fully utilized.
// ---------------------------------------------------------------------------
__global__ void gather2_kernel(const int* __restrict__ row_beg,
                               const int* __restrict__ row_end,
                               const int* __restrict__ csr_src,
                               const float* __restrict__ h2,
                               const float* __restrict__ att_s2,
                               const float* __restrict__ att_d2,
                               const float* __restrict__ b2,
                               float* __restrict__ out, int N) {
    int n = blockIdx.x * 16 + (threadIdx.x >> 4);
    if (n >= N) return;
    int lane = threadIdx.x & 15;
    int beg = row_beg[n];
    int end = row_end[n];
    float a_s = att_s2[0];
    float a_d = att_d2[0];
    float hd = h2[n];
    float num = 0.f, den = 0.f;
    for (int j = beg + lane; j < end; j += 16) {
        int src = csr_src[j];
        float hs = h2[src];
        float lg = hs * a_s + hd * a_d;
        float l = fmaf(NEG_SLOPE, fminf(lg, 0.f), fmaxf(lg, 0.f));
        float w = __expf(l);
        num += w * hs;
        den += w;
    }
#pragma unroll
    for (int off = 8; off >= 1; off >>= 1) {
        num += __shfl_xor(num, off);
        den += __shfl_xor(den, off);
    }
    if (lane == 0) out[n] = num / (den + 1e-16f) + b2[0];
}

extern "C" void kernel_launch(void* const* d_in, const int* in_sizes, int n_in,
                              void* d_out, int out_size, void* d_ws, size_t ws_size,
                              hipStream_t stream) {
    const float* x     = (const float*)d_in[0];
    const int*   ei    = (const int*)  d_in[1];
    const float* W1    = (const float*)d_in[2];
    const float* atts1 = (const float*)d_in[3];
    const float* attd1 = (const float*)d_in[4];
    const float* b1    = (const float*)d_in[5];
    const float* W2    = (const float*)d_in[6];
    const float* atts2 = (const float*)d_in[7];
    const float* attd2 = (const float*)d_in[8];
    const float* b2    = (const float*)d_in[9];
    const float* bn_g  = (const float*)d_in[10];
    const float* bn_b  = (const float*)d_in[11];
    const float* bn_m  = (const float*)d_in[12];
    const float* bn_v  = (const float*)d_in[13];

    const int N = in_sizes[0] / 64;     // 100000
    const int E = in_sizes[1] / 2;      // 1600000
    const int T = E + N;
    const int NBK = (N + 255) >> BK_SHIFT;            // 256-node buckets
    const int NCH = (T + CHUNK - 1) / CHUNK;          // binning blocks
    const int NGB = (N + 7) / 8;                      // gemm blocks

    // workspace layout (manual alignment)
    char* p = (char*)d_ws;
    auto alloc = [&](size_t bytes, size_t align) -> void* {
        uintptr_t q = ((uintptr_t)p + align - 1) & ~(uintptr_t)(align - 1);
        p = (char*)(q + bytes);
        return (void*)q;
    };
    _Float16* h0      = (_Float16*)alloc((size_t)N * 128 * 2, 16);
    float* as1        = (float*)alloc((size_t)N * 4 * 4, 16);
    float* ad1        = (float*)alloc((size_t)N * 4 * 4, 16);
    float* h2         = (float*)alloc((size_t)N * 4, 16);
    float* pre0       = (float*)alloc(128 * 4, 16);
    float* pre1       = (float*)alloc(128 * 4, 16);
    int*   row_beg    = (int*)alloc((size_t)N * 4, 16);
    int*   row_end    = (int*)alloc((size_t)N * 4, 16);
    int*   bucket_cur = (int*)alloc((size_t)MAXBK * 4, 16);
    unsigned int* binned = (unsigned int*)alloc((size_t)NBK * CAP * 4, 16);
    int*   csr_src    = (int*)alloc((size_t)NBK * CAP * 4, 16);

    prep_kernel<<<1, 512, 0, stream>>>(b1, bn_g, bn_b, bn_m, bn_v,
                                       pre0, pre1, bucket_cur);

    gemm_bin_kernel<<<NCH + NGB, 256, 0, stream>>>(
        x, W1, atts1, attd1, h0, as1, ad1, N,
        ei, E, NBK, bucket_cur, binned, NCH);

    csr_kernel<<<NBK, 1024, 0, stream>>>(binned, bucket_cur, N,
                                         row_beg, row_end, csr_src);

    gather1_kernel<<<(N + 3) / 4, 256, 0, stream>>>(
        row_beg, row_end, csr_src, (const half4*)h0, as1, ad1, pre0, pre1,
        W2, h2, N);

    gather2_kernel<<<(N + 15) / 16, 256, 0, stream>>>(
        row_beg, row_end, csr_src, h2, atts2, attd2, b2, (float*)d_out, N);
}